// Round 10
// baseline (2227.321 us; speedup 1.0000x reference)
//
#include <hip/hip_runtime.h>
#include <hip/hip_bf16.h>
#include <cstddef>

typedef __hip_bfloat16 bf16;

// ---------------- problem constants ----------------
#define D_MODEL 1048
#define P_DIM   1048
#define NLAYER  3
#define BSZ     4
#define LSEQ    4096
#define BL      (BSZ*LSEQ)                 // 16384 rows
#define BLD     ((size_t)BL*D_MODEL)       // unpadded elements
#define KP      1056                       // padded K / row stride (33*32)
#define NP      1152                       // padded N for weights (9*128)
#define BLA     ((size_t)BL*KP)            // padded activation elements
#define NPKP    ((size_t)NP*KP)            // padded weight elements

// scan chunking
#define NC      64
#define CL      (LSEQ/NC)                  // 64
#define NSCAN   (BSZ*NC*P_DIM)
#define P2      (P_DIM/2)                  // 524 pairs
#define NSCAN2  (BSZ*NC*P2)

typedef __attribute__((ext_vector_type(8))) short short8;
typedef __attribute__((ext_vector_type(4))) float f32x4;

// ---- GEMM geometry: 256x128 block, wave tile 128x64 (acc[8][4]) ----
// LDS-bytes-per-FLOP lever: 12 KB fragment reads per 32 MFMA/wave
// (vs 8 KB per 16 at the old 64x64 wave tile) = 1.33x better.
#define TM 256
#define TN 128
#define TK 32
#define ASH2 (TM*TK)                       // A tile: 8192 shorts (16 KB)
#define WSH  (TN*TK)                       // W tile: 4096 shorts (8 KB)
#define SLOTC (ASH2 + WSH)                 // 24 KB slot (single W)
#define SLOT2 (ASH2 + 2*WSH)               // 32 KB slot (dual W)
#define KSTEPS  (KP/TK)                    // 33 K sub-steps, no tail
#define NGEMM ((BL/TM)*(NP/TN))            // 64*9 = 576 blocks

__device__ __forceinline__ float gelu_f(float x) {
    return 0.5f * x * (1.f + erff(x * 0.70710678118654752f));
}

// XCD-aware mapping (576 blocks): 9 consecutive blocks on one XCD share an
// A m-panel (xcd = blockId % 8 round-robin; 72 blocks per XCD).
__device__ __forceinline__ void tile_coords(int id, int& m0, int& n0) {
    int xcd  = id & 7;
    int slot = id >> 3;          // 0..71
    int xg   = slot / 9;         // 0..7
    int j    = slot - xg*9;      // 0..8
    m0 = (xg*8 + xcd) * TM;
    n0 = j * TN;
}

// ---------------- staging via global_load_lds ----------------
// LDS dest linear; bank-deswizzle applied to the GLOBAL source column
// (slot s of row r holds source col ((s ^ (r>>1))&3)*8 — verified relation).
__device__ __forceinline__ void stageA_t256(
    const bf16* __restrict__ src, int row0, int k0, short* lds, int tid)
{
#pragma unroll
    for (int c0 = 0; c0 < 4; ++c0) {
        int c = tid + 256*c0;             // 0..1023 chunks of 16B
        int r = c >> 2;                   // 0..255
        int col = ((c ^ (r >> 1)) & 3) * 8;
        __builtin_amdgcn_global_load_lds(
            (const __attribute__((address_space(1))) void*)(src + (size_t)(row0 + r)*KP + k0 + col),
            (__attribute__((address_space(3))) void*)(lds + c*8), 16, 0, 0);
    }
}
__device__ __forceinline__ void stageW_t256(
    const bf16* __restrict__ src, int row0, int k0, short* lds, int tid)
{
#pragma unroll
    for (int c0 = 0; c0 < 2; ++c0) {
        int c = tid + 256*c0;             // 0..511
        int r = c >> 2;                   // 0..127
        int col = ((c ^ (r >> 1)) & 3) * 8;
        __builtin_amdgcn_global_load_lds(
            (const __attribute__((address_space(1))) void*)(src + (size_t)(row0 + r)*KP + k0 + col),
            (__attribute__((address_space(3))) void*)(lds + c*8), 16, 0, 0);
    }
}
// 512-thread variants (gemm2o)
__device__ __forceinline__ void stageA_t512(
    const bf16* __restrict__ src, int row0, int k0, short* lds, int tid)
{
#pragma unroll
    for (int c0 = 0; c0 < 2; ++c0) {
        int c = tid + 512*c0;             // 0..1023
        int r = c >> 2;
        int col = ((c ^ (r >> 1)) & 3) * 8;
        __builtin_amdgcn_global_load_lds(
            (const __attribute__((address_space(1))) void*)(src + (size_t)(row0 + r)*KP + k0 + col),
            (__attribute__((address_space(3))) void*)(lds + c*8), 16, 0, 0);
    }
}
__device__ __forceinline__ void stageW_t512(
    const bf16* __restrict__ src, int row0, int k0, short* lds, int tid)
{
    int r = tid >> 2;                     // 0..127
    int col = ((tid ^ (r >> 1)) & 3) * 8;
    __builtin_amdgcn_global_load_lds(
        (const __attribute__((address_space(1))) void*)(src + (size_t)(row0 + r)*KP + k0 + col),
        (__attribute__((address_space(3))) void*)(lds + tid*8), 16, 0, 0);
}

// ---------------- MFMA sub-step (one TK=32 slice, wave tile 128x64) --------
// qs = (quad ^ ((row_in>>1)&3)) * 8 (wm/wn multiples of 64/128 preserve it).
__device__ __forceinline__ void mfma_big(
    const short* As, const short* Ws, f32x4 (&acc)[8][4],
    int wm, int wn, int row_in, int qs)
{
    short8 a[8], b[4];
#pragma unroll
    for (int i = 0; i < 8; ++i)
        a[i] = *(const short8*)&As[(wm + i*16 + row_in)*TK + qs];
#pragma unroll
    for (int j = 0; j < 4; ++j)
        b[j] = *(const short8*)&Ws[(wn + j*16 + row_in)*TK + qs];
#pragma unroll
    for (int i = 0; i < 8; ++i)
#pragma unroll
        for (int j = 0; j < 4; ++j)
            acc[i][j] = __builtin_amdgcn_mfma_f32_16x16x32_bf16(a[i], b[j], acc[i][j], 0, 0, 0);
}

// ---------------- dual-output GEMM: acc = A@W^T for W0 (waves 0-3) and
// W1 (waves 4-7); each wave owns a 128x64 output region.
// MODE 0: store both (pads zeroed).  MODE 1: O0 = acc0 * gelu(acc1) via
// 4-round LDS exchange (f32 exact).
template <int MODE>
__global__ __launch_bounds__(512, 2) void gemm2o_k(
    const bf16* __restrict__ A, const bf16* __restrict__ W0,
    const bf16* __restrict__ W1,
    bf16* __restrict__ O0, bf16* __restrict__ O1, int N)
{
    __shared__ __align__(16) short smem[2*SLOT2];   // 64 KB
    const int tid  = threadIdx.x;
    int m0, n0;
    tile_coords(blockIdx.x, m0, n0);
    const int wave = tid >> 6, lane = tid & 63;
    const int g = wave >> 2;             // 0: W0, 1: W1
    const int u = wave & 3;
    const int wm = (u >> 1) * 128, wn = (u & 1) * 64;
    const int row_in = lane & 15;
    const int qs = (((lane >> 4) ^ (lane >> 1)) & 3) * 8;

    f32x4 acc[8][4] = {};

#define STG2(s) { int _s=(s); short* _b = smem + (_s&1)*SLOT2; \
    stageA_t512(A,  m0, _s*TK, _b, tid); \
    stageW_t512(W0, n0, _s*TK, _b + ASH2, tid); \
    stageW_t512(W1, n0, _s*TK, _b + ASH2 + WSH, tid); }

    STG2(0); STG2(1);                    // 8 loads/thread in flight
    for (int s = 0; s < KSTEPS - 1; ++s) {
        asm volatile("s_waitcnt vmcnt(4)" ::: "memory");   // tile s landed
        __builtin_amdgcn_s_barrier();
        short* base = smem + (s & 1)*SLOT2;
        __builtin_amdgcn_s_setprio(1);
        mfma_big(base, base + ASH2 + g*WSH, acc, wm, wn, row_in, qs);
        __builtin_amdgcn_s_setprio(0);
        __builtin_amdgcn_s_barrier();                      // slot free
        if (s < KSTEPS - 2) STG2(s + 2);
    }
    asm volatile("s_waitcnt vmcnt(0)" ::: "memory");
    __builtin_amdgcn_s_barrier();
    {
        short* base = smem + ((KSTEPS-1) & 1)*SLOT2;
        __builtin_amdgcn_s_setprio(1);
        mfma_big(base, base + ASH2 + g*WSH, acc, wm, wn, row_in, qs);
        __builtin_amdgcn_s_setprio(0);
    }
#undef STG2

    const int quad = lane >> 4;
    if (MODE == 0) {
        bf16* O = g ? O1 : O0;
#pragma unroll
        for (int i = 0; i < 8; ++i) {
#pragma unroll
            for (int j = 0; j < 4; ++j) {
                int n = n0 + wn + j*16 + row_in;
#pragma unroll
                for (int r = 0; r < 4; ++r) {
                    int m = m0 + wm + i*16 + quad*4 + r;
                    size_t o = (size_t)m*KP + n;
                    if (n < N)        O[o] = __float2bfloat16(acc[i][j][r]);
                    else if (n < KP)  O[o] = __float2bfloat16(0.f);
                }
            }
        }
    } else {
        // 4 exchange rounds (2 i's per round, 32 KB each) through smem.
        // Partner waves u (g=0) and u+4 (g=1) share (wm,wn,lane) mapping.
        f32x4* xb = (f32x4*)smem;
#pragma unroll
        for (int ih = 0; ih < 4; ++ih) {
            __syncthreads();
            if (g) {
#pragma unroll
                for (int il = 0; il < 2; ++il)
#pragma unroll
                    for (int j = 0; j < 4; ++j)
                        xb[(((u*2 + il)*4 + j) << 6) + lane] = acc[2*ih + il][j];
            }
            __syncthreads();
            if (!g) {
#pragma unroll
                for (int il = 0; il < 2; ++il) {
                    int i = 2*ih + il;
#pragma unroll
                    for (int j = 0; j < 4; ++j) {
                        f32x4 gv = xb[(((u*2 + il)*4 + j) << 6) + lane];
                        int n = n0 + wn + j*16 + row_in;
#pragma unroll
                        for (int r = 0; r < 4; ++r) {
                            int m = m0 + wm + i*16 + quad*4 + r;
                            size_t o = (size_t)m*KP + n;
                            if (n < N)        O0[o] = __float2bfloat16(acc[i][j][r] * gelu_f(gv[r]));
                            else if (n < KP)  O0[o] = __float2bfloat16(0.f);
                        }
                    }
                }
            }
        }
    }
}

// ---------------- dual-input GEMM + sepi epilogue ----------------
// acc = A0@W0^T + A1@W1^T;  O = gelu(acc + dv[n]*fx) + fx   (pads zeroed)
// 66-step flattened loop; 4 waves x 128x64 wave tile.
__global__ __launch_bounds__(256, 2) void gemmC_k(
    const bf16* __restrict__ A0, const bf16* __restrict__ W0,
    const bf16* __restrict__ A1, const bf16* __restrict__ W1,
    const bf16* __restrict__ fx, const float* __restrict__ dv,
    bf16* __restrict__ O, int N)
{
    __shared__ __align__(16) short smem[2*SLOTC];   // 48 KB
    const int tid  = threadIdx.x;
    int m0, n0;
    tile_coords(blockIdx.x, m0, n0);
    const int wave = tid >> 6, lane = tid & 63;
    const int wm = (wave >> 1) * 128, wn = (wave & 1) * 64;
    const int row_in = lane & 15;
    const int qs = (((lane >> 4) ^ (lane >> 1)) & 3) * 8;

    f32x4 acc[8][4] = {};

    const int NST = 2*KSTEPS;     // 66 sub-steps
#define STGC(s) { int _s=(s); \
    const bf16* _A = (_s >= KSTEPS) ? A1 : A0; \
    const bf16* _W = (_s >= KSTEPS) ? W1 : W0; \
    int _kk = (_s >= KSTEPS ? _s - KSTEPS : _s)*TK; \
    short* _b = smem + (_s&1)*SLOTC; \
    stageA_t256(_A, m0, _kk, _b, tid); \
    stageW_t256(_W, n0, _kk, _b + ASH2, tid); }

    STGC(0); STGC(1);                    // 12 loads/thread in flight
    for (int s = 0; s < NST - 1; ++s) {
        asm volatile("s_waitcnt vmcnt(6)" ::: "memory");
        __builtin_amdgcn_s_barrier();
        short* base = smem + (s & 1)*SLOTC;
        __builtin_amdgcn_s_setprio(1);
        mfma_big(base, base + ASH2, acc, wm, wn, row_in, qs);
        __builtin_amdgcn_s_setprio(0);
        __builtin_amdgcn_s_barrier();
        if (s < NST - 2) STGC(s + 2);
    }
    asm volatile("s_waitcnt vmcnt(0)" ::: "memory");
    __builtin_amdgcn_s_barrier();
    {
        short* base = smem + ((NST-1) & 1)*SLOTC;
        __builtin_amdgcn_s_setprio(1);
        mfma_big(base, base + ASH2, acc, wm, wn, row_in, qs);
        __builtin_amdgcn_s_setprio(0);
    }
#undef STGC

    const int quad = lane >> 4;
#pragma unroll
    for (int i = 0; i < 8; ++i) {
#pragma unroll
        for (int j = 0; j < 4; ++j) {
            int n = n0 + wn + j*16 + row_in;
#pragma unroll
            for (int r = 0; r < 4; ++r) {
                int m = m0 + wm + i*16 + quad*4 + r;
                size_t o = (size_t)m*KP + n;
                if (n < N) {
                    float f = __bfloat162float(fx[o]);
                    float t = acc[i][j][r] + dv[n]*f;
                    O[o] = __float2bfloat16(gelu_f(t) + f);
                } else if (n < KP) {
                    O[o] = __float2bfloat16(0.f);
                }
            }
        }
    }
}

// ---------------- single GEMM + residual epilogue: h += acc + fy -----------
__global__ __launch_bounds__(256, 2) void gemmD_k(
    const bf16* __restrict__ A, const bf16* __restrict__ W,
    const bf16* __restrict__ fy, float* __restrict__ h, int N)
{
    __shared__ __align__(16) short smem[2*SLOTC];   // 48 KB
    const int tid  = threadIdx.x;
    int m0, n0;
    tile_coords(blockIdx.x, m0, n0);
    const int wave = tid >> 6, lane = tid & 63;
    const int wm = (wave >> 1) * 128, wn = (wave & 1) * 64;
    const int row_in = lane & 15;
    const int qs = (((lane >> 4) ^ (lane >> 1)) & 3) * 8;

    f32x4 acc[8][4] = {};

#define STGD(s) { int _s=(s); short* _b = smem + (_s&1)*SLOTC; \
    stageA_t256(A, m0, _s*TK, _b, tid); \
    stageW_t256(W, n0, _s*TK, _b + ASH2, tid); }

    STGD(0); STGD(1);
    for (int s = 0; s < KSTEPS - 1; ++s) {
        asm volatile("s_waitcnt vmcnt(6)" ::: "memory");
        __builtin_amdgcn_s_barrier();
        short* base = smem + (s & 1)*SLOTC;
        __builtin_amdgcn_s_setprio(1);
        mfma_big(base, base + ASH2, acc, wm, wn, row_in, qs);
        __builtin_amdgcn_s_setprio(0);
        __builtin_amdgcn_s_barrier();
        if (s < KSTEPS - 2) STGD(s + 2);
    }
    asm volatile("s_waitcnt vmcnt(0)" ::: "memory");
    __builtin_amdgcn_s_barrier();
    {
        short* base = smem + ((KSTEPS-1) & 1)*SLOTC;
        __builtin_amdgcn_s_setprio(1);
        mfma_big(base, base + ASH2, acc, wm, wn, row_in, qs);
        __builtin_amdgcn_s_setprio(0);
    }
#undef STGD

    const int quad = lane >> 4;
#pragma unroll
    for (int i = 0; i < 8; ++i) {
#pragma unroll
        for (int j = 0; j < 4; ++j) {
            int n = n0 + wn + j*16 + row_in;
            if (n >= N) continue;
#pragma unroll
            for (int r = 0; r < 4; ++r) {
                int m = m0 + wm + i*16 + quad*4 + r;
                float f = __bfloat162float(fy[(size_t)m*KP + n]);
                h[(size_t)m*D_MODEL + n] += acc[i][j][r] + f;
            }
        }
    }
}

// ---------------- merged per-layer weight precompute -----------------------
// z=0: SSM prep (Bbar re/im + abar).  z=1..5: fp32->bf16 weight conversion
// (C_re, -C_im, WencA, WencG, Wdec) into w5.
__global__ __launch_bounds__(256) void prepconv_k(
    const float* __restrict__ lam_re, const float* __restrict__ lam_im,
    const float* __restrict__ log_step,
    const float* __restrict__ B_re, const float* __restrict__ B_im,
    bf16* __restrict__ bbar_re, bf16* __restrict__ bbar_im,
    float* __restrict__ abar,
    const float* __restrict__ s0, const float* __restrict__ s1,
    const float* __restrict__ s2, const float* __restrict__ s3,
    const float* __restrict__ s4, bf16* __restrict__ w5)
{
    size_t idx = (size_t)blockIdx.x*256 + threadIdx.x;
    if (idx >= NPKP) return;
    int z = blockIdx.z;
    int p = (int)(idx / KP);
    int d = (int)(idx - (size_t)p*KP);
    if (z == 0) {
        if (p >= P_DIM || d >= D_MODEL) {
            bbar_re[idx] = __float2bfloat16(0.f);
            bbar_im[idx] = __float2bfloat16(0.f);
            return;
        }
        float lr = lam_re[p], li = lam_im[p];
        float st = expf(log_step[p]);
        float er = expf(lr*st);
        float ar = er * cosf(li*st);
        float ai = er * sinf(li*st);
        if (d == 0) { abar[p] = ar; abar[P_DIM + p] = ai; }
        float den = lr*lr + li*li;
        float xr = ar - 1.f, xi = ai;
        float cr = (xr*lr + xi*li) / den;
        float ci = (xi*lr - xr*li) / den;
        float br = B_re[(size_t)p*D_MODEL + d], bi = B_im[(size_t)p*D_MODEL + d];
        bbar_re[idx] = __float2bfloat16(cr*br - ci*bi);
        bbar_im[idx] = __float2bfloat16(cr*bi + ci*br);
    } else {
        int w = z - 1;
        const float* src = (w == 0) ? s0 : (w == 1) ? s1 : (w == 2) ? s2 : (w == 3) ? s3 : s4;
        float scale = (w == 1) ? -1.f : 1.f;
        float v = (p < D_MODEL && d < D_MODEL) ? scale*src[(size_t)p*D_MODEL + d] : 0.f;
        w5[(size_t)w*NPKP + idx] = __float2bfloat16(v);
    }
}

// ---------------- reductions ----------------
__device__ __forceinline__ float2 block_reduce2(float a, float b) {
    __syncthreads();   // safe for repeated calls (shared reuse)
    for (int off = 32; off; off >>= 1) {
        a += __shfl_down(a, off, 64);
        b += __shfl_down(b, off, 64);
    }
    __shared__ float sa[4], sb[4];
    int lane = threadIdx.x & 63, wv = threadIdx.x >> 6;
    if (lane == 0) { sa[wv] = a; sb[wv] = b; }
    __syncthreads();
    if (threadIdx.x == 0) {
        sa[0] = sa[0]+sa[1]+sa[2]+sa[3];
        sb[0] = sb[0]+sb[1]+sb[2]+sb[3];
    }
    __syncthreads();
    return make_float2(sa[0], sb[0]);
}

// ---------------- fused double layernorm: fx = LN(LN(h,w1,b1),w2,b2) -------
// ENC=1: additionally computes h = x[row]*ew + eb itself and writes it (layer 0).
template <int ENC>
__global__ __launch_bounds__(256) void ln2x_k(
    const float* __restrict__ xin,
    const float* __restrict__ ew, const float* __restrict__ eb,
    float* __restrict__ hbuf,
    const float* __restrict__ w1, const float* __restrict__ bb1,
    const float* __restrict__ w2, const float* __restrict__ bb2,
    bf16* __restrict__ y)
{
    const size_t row = blockIdx.x;
    float v[5];
    float s = 0.f, ss = 0.f;
    int i = 0;
    if (ENC) {
        float xv = xin[row];
        float* hr = hbuf + row * D_MODEL;
        for (int d = threadIdx.x; d < KP; d += 256, ++i) {
            float t = 0.f;
            if (d < D_MODEL) { t = xv*ew[d] + eb[d]; hr[d] = t; }
            v[i] = t; s += t; ss += t*t;
        }
    } else {
        const float* xr = hbuf + row * D_MODEL;
        for (int d = threadIdx.x; d < KP; d += 256, ++i) {
            float t = (d < D_MODEL) ? xr[d] : 0.f;
            v[i] = t; s += t; ss += t*t;
        }
    }
    float2 r = block_reduce2(s, ss);
    float mu  = r.x * (1.f/D_MODEL);
    float var = r.y * (1.f/D_MODEL) - mu*mu;
    float inv = rsqrtf(var + 1e-5f);
    s = 0.f; ss = 0.f; i = 0;
    for (int d = threadIdx.x; d < KP; d += 256, ++i) {
        float z = (d < D_MODEL) ? (v[i]-mu)*inv*w1[d] + bb1[d] : 0.f;
        v[i] = z; s += z; ss += z*z;
    }
    r = block_reduce2(s, ss);
    mu  = r.x * (1.f/D_MODEL);
    var = r.y * (1.f/D_MODEL) - mu*mu;
    inv = rsqrtf(var + 1e-5f);
    bf16* yr = y + row * KP;
    i = 0;
    for (int d = threadIdx.x; d < KP; d += 256, ++i) {
        float o = (d < D_MODEL) ? (v[i]-mu)*inv*w2[d] + bb2[d] : 0.f;
        yr[d] = __float2bfloat16(o);
    }
}

// ---------------- single layernorm (bf16 in stride KP) ----------------
__global__ __launch_bounds__(256) void ln_k(
    const bf16* __restrict__ x, const float* __restrict__ w,
    const float* __restrict__ b, bf16* __restrict__ y)
{
    const size_t row = blockIdx.x;
    const bf16* xr = x + row * KP;
    float v[5];
    float s = 0.f, ss = 0.f;
    int i = 0;
    for (int d = threadIdx.x; d < KP; d += 256, ++i) {
        float t = (d < D_MODEL) ? __bfloat162float(xr[d]) : 0.f;
        v[i] = t; s += t; ss += t*t;
    }
    float2 r = block_reduce2(s, ss);
    float mu  = r.x * (1.f/D_MODEL);
    float var = r.y * (1.f/D_MODEL) - mu*mu;
    float inv = rsqrtf(var + 1e-5f);
    bf16* yr = y + row * KP;
    i = 0;
    for (int d = threadIdx.x; d < KP; d += 256, ++i) {
        float o = (d < D_MODEL) ? (v[i]-mu)*inv*w[d] + b[d] : 0.f;
        yr[d] = __float2bfloat16(o);
    }
}

// ---------------- chunked parallel scan (2 p per thread, ushort2) ----------
__device__ __forceinline__ float2 bf2f(unsigned int u) {
    unsigned int lo = u << 16, hi = u & 0xffff0000u;
    float2 r;
    r.x = __uint_as_float(lo);
    r.y = __uint_as_float(hi);
    return r;
}
__device__ __forceinline__ unsigned int f2bf2(float a, float b) {
    bf16 ba = __float2bfloat16(a), bb = __float2bfloat16(b);
    unsigned short ua = *(unsigned short*)&ba, ub = *(unsigned short*)&bb;
    return (unsigned int)ua | ((unsigned int)ub << 16);
}

__global__ __launch_bounds__(256) void scan_partial_k(
    const unsigned int* __restrict__ ur, const unsigned int* __restrict__ ui,
    const float* __restrict__ abar,
    float* __restrict__ sum_re, float* __restrict__ sum_im)
{
    int idx = blockIdx.x*256 + threadIdx.x;
    if (idx >= NSCAN2) return;
    int p2 = idx % P2;
    int rest = idx / P2;
    int c = rest % NC, b = rest / NC;
    int p = 2*p2;
    float ar0 = abar[p],   ai0 = abar[P_DIM + p];
    float ar1 = abar[p+1], ai1 = abar[P_DIM + p + 1];
    size_t base = (((size_t)b*LSEQ + (size_t)c*CL)*KP + p) >> 1;   // u32 index
    float s0r = 0.f, s0i = 0.f, s1r = 0.f, s1i = 0.f;
    for (int i = 0; i < CL; ++i) {
        size_t o = base + (size_t)i*(KP/2);
        float2 br = bf2f(ur[o]);
        float2 bi = bf2f(ui[o]);
        float n0r = fmaf(ar0, s0r, fmaf(-ai0, s0i, br.x));
        float n0i = fmaf(ar0, s0i, fmaf( ai0, s0r, bi.x));
        float n1r = fmaf(ar1, s1r, fmaf(-ai1, s1i, br.y));
        float n1i = fmaf(ar1, s1i, fmaf( ai1, s1r, bi.y));
        s0r = n0r; s0i = n0i; s1r = n1r; s1i = n1i;
    }
    size_t so = ((size_t)b*NC + c)*P_DIM + p;
    *(float2*)&sum_re[so] = make_float2(s0r, s1r);
    *(float2*)&sum_im[so] = make_float2(s0i, s1i);
}

__global__ __launch_bounds__(256) void scan_carry_k(
    const float* __restrict__ sum_re, const float* __restrict__ sum_im,
    const float* __restrict__ abar,
    float* __restrict__ car_re, float* __restrict__ car_im)
{
    int idx = blockIdx.x*256 + threadIdx.x;
    if (idx >= BSZ*P_DIM) return;
    int p = idx % P_DIM, b = idx / P_DIM;
    float cr = abar[p], ci = abar[P_DIM + p];
#pragma unroll
    for (int s = 0; s < 6; ++s) {       // a^64 by repeated squaring
        float nr = cr*cr - ci*ci;
        float ni = 2.f*cr*ci;
        cr = nr; ci = ni;
    }
    float xre = 0.f, xim = 0.f;
    size_t base = (size_t)b*NC*P_DIM + p;
    for (int c = 0; c < NC; ++c) {
        size_t o = base + (size_t)c*P_DIM;
        car_re[o] = xre; car_im[o] = xim;
        float sre = sum_re[o], sim = sum_im[o];
        float nr = fmaf(cr, xre, fmaf(-ci, xim, sre));
        float ni = fmaf(cr, xim, fmaf( ci, xre, sim));
        xre = nr; xim = ni;
    }
}

__global__ __launch_bounds__(256) void scan_apply_k(
    unsigned int* __restrict__ ur, unsigned int* __restrict__ ui,
    const float* __restrict__ abar,
    const float* __restrict__ car_re, const float* __restrict__ car_im)
{
    int idx = blockIdx.x*256 + threadIdx.x;
    if (idx >= NSCAN2) return;
    int p2 = idx % P2;
    int rest = idx / P2;
    int c = rest % NC, b = rest / NC;
    int p = 2*p2;
    float ar0 = abar[p],   ai0 = abar[P_DIM + p];
    float ar1 = abar[p+1], ai1 = abar[P_DIM + p + 1];
    size_t co = ((size_t)b*NC + c)*P_DIM + p;
    float2 c_r = *(const float2*)&car_re[co];
    float2 c_i = *(const float2*)&car_im[co];
    float x0r = c_r.x, x0i = c_i.x, x1r = c_r.y, x1i = c_i.y;
    size_t base = (((size_t)b*LSEQ + (size_t)c*CL)*KP + p) >> 1;
    for (int i = 0; i < CL; ++i) {
        size_t o = base + (size_t)i*(KP/2);
        float2 br = bf2f(ur[o]);
        float2 bi = bf2f(ui[o]);
        float n0r = fmaf(ar0, x0r, fmaf(-ai0, x0i, br.x));
        float n0i = fmaf(ar0, x0i, fmaf( ai0, x0r, bi.x));
        float n1r = fmaf(ar1, x1r, fmaf(-ai1, x1i, br.y));
        float n1i = fmaf(ar1, x1i, fmaf( ai1, x1r, bi.y));
        x0r = n0r; x0i = n0i; x1r = n1r; x1i = n1i;
        ur[o] = f2bf2(x0r, x1r);
        ui[o] = f2bf2(x0i, x1i);
    }
}

// ---------------- head ----------------
__global__ void head_init_k(float* out, const float* hb)
{
    if (threadIdx.x < BSZ) out[threadIdx.x] = hb[0];
}

__global__ __launch_bounds__(256) void head_k(
    const float* __restrict__ h, const float* __restrict__ hw,
    float* __restrict__ out)
{
    int b = blockIdx.x;
    int chunk = blockIdx.y;
    const float* hb = h + ((size_t)b*LSEQ + (size_t)chunk*64)*D_MODEL;
    float s = 0.f;
    for (int l = 0; l < 64; ++l) {
        const float* hr = hb + (size_t)l*D_MODEL;
        for (int d = threadIdx.x; d < D_MODEL; d += 256)
            s += hr[d]*hw[d];
    }
    for (int off = 32; off; off >>= 1) s += __shfl_down(s, off, 64);
    __shared__ float sm[4];
    int lane = threadIdx.x & 63, wv = threadIdx.x >> 6;
    if (lane == 0) sm[wv] = s;
    __syncthreads();
    if (threadIdx.x == 0)
        atomicAdd(out + b, (sm[0]+sm[1]+sm[2]+sm[3]) * (1.f/LSEQ));
}

// ---------------- launch ----------------
extern "C" void kernel_launch(void* const* d_in, const int* in_sizes, int n_in,
                              void* d_out, int out_size, void* d_ws, size_t ws_size,
                              hipStream_t stream)
{
    const float* x          = (const float*)d_in[0];
    const float* enc_w      = (const float*)d_in[1];
    const float* enc_b      = (const float*)d_in[2];
    const float* norm_w     = (const float*)d_in[3];
    const float* norm_b     = (const float*)d_in[4];
    const float* attn_w     = (const float*)d_in[5];
    const float* attn_b     = (const float*)d_in[6];
    const float* ff_w       = (const float*)d_in[7];
    const float* ff_b       = (const float*)d_in[8];
    const float* lam_re     = (const float*)d_in[9];
    const float* lam_im     = (const float*)d_in[10];
    const float* log_step   = (const float*)d_in[11];
    const float* B_re       = (const float*)d_in[12];
    const float* B_im       = (const float*)d_in[13];
    const float* C_re       = (const float*)d_in[14];
    const float* C_im       = (const float*)d_in[15];
    const float* Dvec       = (const float*)d_in[16];
    const float* Wenc       = (const float*)d_in[17];
    const float* Wdec       = (const float*)d_in[18];
    const float* head_w     = (const float*)d_in[19];
    const float* head_b     = (const float*)d_in[20];
    float* out = (float*)d_out;

    // ---- workspace (~241 MB) ----
    float* h    = (float*)d_ws;            // BLD fp32
    bf16*  b1   = (bf16*)(h + BLD);        // BLA bf16 each
    bf16*  b2   = b1 + BLA;
    bf16*  b3   = b2 + BLA;
    bf16*  b4   = b3 + BLA;
    bf16*  wbr  = b4 + BLA;                // Bbar re/im
    bf16*  wbi  = wbr + NPKP;
    bf16*  w5   = wbi + NPKP;              // wcr,wci(-),wea,weg,wd contiguous
    bf16*  wcr  = w5;
    bf16*  wci  = w5 + NPKP;
    bf16*  wea  = w5 + 2*NPKP;
    bf16*  weg  = w5 + 3*NPKP;
    bf16*  wd   = w5 + 4*NPKP;
    float* abar = (float*)(w5 + 5*NPKP);   // 2*P fp32
    float* sum_re = abar + 2*P_DIM;
    float* sum_im = sum_re + NSCAN;
    float* car_re = sum_im + NSCAN;
    float* car_im = car_re + NSCAN;

    const int CV   = (int)((NPKP + 255)/256);
    const int SC_G = (NSCAN2 + 255)/256;
    const size_t pd = (size_t)P_DIM*D_MODEL;

    for (int i = 0; i < NLAYER; ++i) {
        const float* WencA = Wenc + (size_t)i*2*pd;
        const float* WencG = WencA + pd;
        // merged SSM prep + 5x weight conversion (one dispatch)
        prepconv_k<<<dim3(CV,1,6), 256, 0, stream>>>(
            lam_re + i*P_DIM, lam_im + i*P_DIM, log_step + i*P_DIM,
            B_re + i*pd, B_im + i*pd, wbr, wbi, abar,
            C_re + i*pd, C_im + i*pd, WencA, WencG, Wdec + i*pd, w5);

        // fx = LN(LN(h)); layer 0 computes and writes h = x*ew+eb itself
        if (i == 0)
            ln2x_k<1><<<BL, 256, 0, stream>>>(x, enc_w, enc_b, h,
                norm_w + i*D_MODEL, norm_b + i*D_MODEL,
                attn_w + i*D_MODEL, attn_b + i*D_MODEL, b2);
        else
            ln2x_k<0><<<BL, 256, 0, stream>>>(nullptr, nullptr, nullptr, h,
                norm_w + i*D_MODEL, norm_b + i*D_MODEL,
                attn_w + i*D_MODEL, attn_b + i*D_MODEL, b2);

        // Bu_re, Bu_im in one dual-output GEMM
        gemm2o_k<0><<<NGEMM, 512, 0, stream>>>(b2, wbr, wbi, b1, b3, P_DIM);

        // chunked parallel scan (in-place on b1/b3)
        scan_partial_k<<<SC_G, 256, 0, stream>>>((unsigned int*)b1, (unsigned int*)b3,
                                                 abar, sum_re, sum_im);
        scan_carry_k<<<(BSZ*P_DIM + 255)/256, 256, 0, stream>>>(sum_re, sum_im, abar, car_re, car_im);
        scan_apply_k<<<SC_G, 256, 0, stream>>>((unsigned int*)b1, (unsigned int*)b3,
                                               abar, car_re, car_im);

        // z2 = gelu(xs_re@C_re^T + xs_im@(-C_im)^T + Dvec*fx) + fx
        gemmC_k<<<NGEMM, 256, 0, stream>>>(b1, wcr, b3, wci, b2, Dvec + i*D_MODEL, b4, D_MODEL);

        // fy = LN(z2)
        ln_k<<<BL, 256, 0, stream>>>(b4, ff_w + i*D_MODEL, ff_b + i*D_MODEL, b1);

        // GEGLU MLP: b2 = (fy@WencA^T) * gelu(fy@WencG^T)
        gemm2o_k<1><<<NGEMM, 512, 0, stream>>>(b1, wea, weg, b2, nullptr, D_MODEL);

        // h += b2@Wdec^T + fy
        gemmD_k<<<NGEMM, 256, 0, stream>>>(b2, wd, b1, h, D_MODEL);
    }

    head_init_k<<<1, 64, 0, stream>>>(out, head_b);
    head_k<<<dim3(BSZ, 64), 256, 0, stream>>>(h, head_w, out);
}

// Round 11
// 1907.509 us; speedup vs baseline: 1.1677x; 1.1677x over previous
//
#include <hip/hip_runtime.h>
#include <hip/hip_bf16.h>
#include <cstddef>

typedef __hip_bfloat16 bf16;

// ---------------- problem constants ----------------
#define D_MODEL 1048
#define P_DIM   1048
#define NLAYER  3
#define BSZ     4
#define LSEQ    4096
#define BL      (BSZ*LSEQ)                 // 16384 rows
#define BLD     ((size_t)BL*D_MODEL)       // unpadded elements
#define KP      1056                       // padded K / row stride (33*32)
#define NP      1152                       // padded N for weights (9*128)
#define BLA     ((size_t)BL*KP)            // padded activation elements
#define NPKP    ((size_t)NP*KP)            // padded weight elements

// scan chunking
#define NC      64
#define CL      (LSEQ/NC)                  // 64
#define NSCAN   (BSZ*NC*P_DIM)
#define P2      (P_DIM/2)                  // 524 pairs
#define NSCAN2  (BSZ*NC*P2)

typedef __attribute__((ext_vector_type(8))) short short8;
typedef __attribute__((ext_vector_type(4))) float f32x4;

#define TM 128
#define TN 128
#define TK 32
#define TILE_SH (TM*TK)                    // 4096 shorts = 8 KB per sub-tile
#define NGEMM   ((BL/TM)*(NP/TN))          // 1152 blocks
#define KSTEPS  (KP/TK)                    // 33 K sub-steps, no tail

__device__ __forceinline__ float gelu_f(float x) {
    return 0.5f * x * (1.f + erff(x * 0.70710678118654752f));
}

// XCD-aware mapping (1152 blocks): 9 consecutive blocks on one XCD share an
// A m-tile (xcd = blockId % 8 round-robin).
__device__ __forceinline__ void tile_coords(int id, int& m0, int& n0) {
    int xcd  = id & 7;
    int slot = id >> 3;          // 0..143
    int xg   = slot / 9;         // 0..15
    int j    = slot - xg*9;      // 0..8
    m0 = (xg*8 + xcd) * TM;
    n0 = j * TN;
}

// ---------------- staging: one 128x32 bf16 tile via global_load_lds --------
// LDS dest linear; bank-deswizzle applied to the GLOBAL source column.
__device__ __forceinline__ void stage_tile(
    const bf16* __restrict__ src, int row0, int k0, short* lds, int tid)
{
#pragma unroll
    for (int c = 0; c < 2; ++c) {
        int chunk = tid + 256*c;          // 0..511
        int r = chunk >> 2;
        int col = ((chunk ^ (r >> 1)) & 3) * 8;   // pre-swizzled source col
        __builtin_amdgcn_global_load_lds(
            (const __attribute__((address_space(1))) void*)(src + (size_t)(row0 + r)*KP + k0 + col),
            (__attribute__((address_space(3))) void*)(lds + chunk*8), 16, 0, 0);
    }
}

// 512-thread variant: exactly one 16B load per thread per tile.
__device__ __forceinline__ void stage512(
    const bf16* __restrict__ src, int row0, int k0, short* lds, int tid)
{
    int r = tid >> 2;
    int col = ((tid ^ (r >> 1)) & 3) * 8;
    __builtin_amdgcn_global_load_lds(
        (const __attribute__((address_space(1))) void*)(src + (size_t)(row0 + r)*KP + k0 + col),
        (__attribute__((address_space(3))) void*)(lds + tid*8), 16, 0, 0);
}

// ---------------- MFMA sub-step (one TK=32 slice) ----------------
// qs = (quad ^ ((row_in>>1)&3)) * 8 : bank-conflict-free swizzled read offset.
__device__ __forceinline__ void mfma_step1(
    const short* As, const short* Ws, f32x4 (&acc)[4][4],
    int wm, int wn, int row_in, int qs)
{
    short8 a[4], b[4];
#pragma unroll
    for (int i = 0; i < 4; ++i) {
        a[i] = *(const short8*)&As[(wm + i*16 + row_in)*TK + qs];
        b[i] = *(const short8*)&Ws[(wn + i*16 + row_in)*TK + qs];
    }
#pragma unroll
    for (int i = 0; i < 4; ++i)
#pragma unroll
        for (int j = 0; j < 4; ++j)
            acc[i][j] = __builtin_amdgcn_mfma_f32_16x16x32_bf16(a[i], b[j], acc[i][j], 0, 0, 0);
}

#define ROT3(p0, p1, p2) { short* _t = p0; p0 = p1; p1 = p2; p2 = _t; }

// ---------------- dual-output GEMM (r3 best-measured config) ---------------
// 512 threads / 8 waves, n-split: waves wc<2 compute the W0 half, wc>=2 the
// W1 half; depth-3 triple-buffered, counted vmcnt.
// MODE 0: store both halves (pads zeroed).  MODE 1: O0 = acc0 * gelu(acc1),
// acc1 exchanged wave-pair-wise through LDS (f32 exact).
template <int MODE>
__global__ __launch_bounds__(512, 4) void gemm2o_k(
    const bf16* __restrict__ A, const bf16* __restrict__ W0,
    const bf16* __restrict__ W1,
    bf16* __restrict__ O0, bf16* __restrict__ O1, int N)
{
    __shared__ __align__(16) short smem[9*TILE_SH];   // 72 KB
    short *pA  = smem,             *pA1  = smem + TILE_SH,   *pA2  = smem + 2*TILE_SH;
    short *pW0 = smem + 3*TILE_SH, *pW01 = smem + 4*TILE_SH, *pW02 = smem + 5*TILE_SH;
    short *pW1 = smem + 6*TILE_SH, *pW11 = smem + 7*TILE_SH, *pW12 = smem + 8*TILE_SH;
    const int tid  = threadIdx.x;
    int m0, n0;
    tile_coords(blockIdx.x, m0, n0);
    const int wave = tid >> 6, lane = tid & 63;
    const int wr = wave >> 2, wc = wave & 3;
    const int wm = wr * 64;
    const int wn = (wc & 1) * 64;
    const bool useW1 = (wc >= 2);
    const int row_in = lane & 15;
    const int qs = (((lane >> 4) ^ (lane >> 1)) & 3) * 8;

    f32x4 acc[4][4] = {};

    // prologue: stage tiles 0,1,2 (3 loads/thread per tile; 9 in flight)
    stage512(A,  m0, 0,    pA,   tid);
    stage512(W0, n0, 0,    pW0,  tid);
    stage512(W1, n0, 0,    pW1,  tid);
    stage512(A,  m0, TK,   pA1,  tid);
    stage512(W0, n0, TK,   pW01, tid);
    stage512(W1, n0, TK,   pW11, tid);
    stage512(A,  m0, 2*TK, pA2,  tid);
    stage512(W0, n0, 2*TK, pW02, tid);
    stage512(W1, n0, 2*TK, pW12, tid);

    for (int s = 0; s <= KSTEPS - 4; ++s) {           // s = 0..29
        asm volatile("s_waitcnt vmcnt(6)" ::: "memory");   // tile s landed
        __builtin_amdgcn_s_barrier();
        mfma_step1(pA, useW1 ? pW1 : pW0, acc, wm, wn, row_in, qs);
        __builtin_amdgcn_s_barrier();                  // all waves done with buf
        const int k0 = (s + 3) * TK;                   // tiles 3..32
        stage512(A,  m0, k0, pA,  tid);
        stage512(W0, n0, k0, pW0, tid);
        stage512(W1, n0, k0, pW1, tid);
        ROT3(pA,  pA1,  pA2);
        ROT3(pW0, pW01, pW02);
        ROT3(pW1, pW11, pW12);
    }
    // peeled steps KSTEPS-3, KSTEPS-2, KSTEPS-1
    asm volatile("s_waitcnt vmcnt(6)" ::: "memory");
    __builtin_amdgcn_s_barrier();
    mfma_step1(pA, useW1 ? pW1 : pW0, acc, wm, wn, row_in, qs);
    asm volatile("s_waitcnt vmcnt(3)" ::: "memory");
    __builtin_amdgcn_s_barrier();
    mfma_step1(pA1, useW1 ? pW11 : pW01, acc, wm, wn, row_in, qs);
    asm volatile("s_waitcnt vmcnt(0)" ::: "memory");
    __builtin_amdgcn_s_barrier();
    mfma_step1(pA2, useW1 ? pW12 : pW02, acc, wm, wn, row_in, qs);

    const int quad = lane >> 4;
    if (MODE == 0) {
        bf16* O = useW1 ? O1 : O0;
#pragma unroll
        for (int i = 0; i < 4; ++i) {
#pragma unroll
            for (int j = 0; j < 4; ++j) {
                int n = n0 + wn + j*16 + row_in;
#pragma unroll
                for (int r = 0; r < 4; ++r) {
                    int m = m0 + wm + i*16 + quad*4 + r;
                    size_t o = (size_t)m*KP + n;
                    if (n < N)        O[o] = __float2bfloat16(acc[i][j][r]);
                    else if (n < KP)  O[o] = __float2bfloat16(0.f);
                }
            }
        }
    } else {
        // exchange acc1 (gate) from useW1 waves to partner waves via LDS.
        // pair id pp = wr*2 + (wc&1); partner shares (wm, wn) so lane maps
        // element-exact. Two rounds of 32 KB (i-halves).
        f32x4* xb = (f32x4*)smem;
        const int pp = wr*2 + (wc & 1);
#pragma unroll
        for (int ih = 0; ih < 2; ++ih) {
            __syncthreads();
            if (useW1) {
#pragma unroll
                for (int il = 0; il < 2; ++il)
#pragma unroll
                    for (int j = 0; j < 4; ++j)
                        xb[(((pp*2 + il)*4 + j) << 6) + lane] = acc[2*ih + il][j];
            }
            __syncthreads();
            if (!useW1) {
#pragma unroll
                for (int il = 0; il < 2; ++il) {
                    int i = 2*ih + il;
#pragma unroll
                    for (int j = 0; j < 4; ++j) {
                        f32x4 g = xb[(((pp*2 + il)*4 + j) << 6) + lane];
                        int n = n0 + wn + j*16 + row_in;
#pragma unroll
                        for (int r = 0; r < 4; ++r) {
                            int m = m0 + wm + i*16 + quad*4 + r;
                            size_t o = (size_t)m*KP + n;
                            if (n < N)        O0[o] = __float2bfloat16(acc[i][j][r] * gelu_f(g[r]));
                            else if (n < KP)  O0[o] = __float2bfloat16(0.f);
                        }
                    }
                }
            }
        }
    }
}

// ---------------- dual-input GEMM + sepi epilogue (r1 best-measured) -------
// acc = A0@W0^T + A1@W1^T;  O = gelu(acc + dv[n]*fx) + fx   (pads zeroed)
// Depth-2 double-buffer, counted vmcnt, 66-step flattened K loop.
__global__ __launch_bounds__(256, 2) void gemmC_k(
    const bf16* __restrict__ A0, const bf16* __restrict__ W0,
    const bf16* __restrict__ A1, const bf16* __restrict__ W1,
    const bf16* __restrict__ fx, const float* __restrict__ dv,
    bf16* __restrict__ O, int N)
{
    __shared__ __align__(16) short As[2][TILE_SH];
    __shared__ __align__(16) short Ws[2][TILE_SH];
    const int tid  = threadIdx.x;
    int m0, n0;
    tile_coords(blockIdx.x, m0, n0);
    const int wave = tid >> 6, lane = tid & 63;
    const int wm = (wave >> 1) * 64, wn = (wave & 1) * 64;
    const int row_in = lane & 15;
    const int qs = (((lane >> 4) ^ (lane >> 1)) & 3) * 8;

    f32x4 acc[4][4] = {};

    const int NST = 2*KSTEPS;     // 66 sub-steps
    stage_tile(A0, m0, 0,  As[0], tid);
    stage_tile(W0, n0, 0,  Ws[0], tid);
    stage_tile(A0, m0, TK, As[1], tid);
    stage_tile(W0, n0, TK, Ws[1], tid);

    for (int s = 0; s < NST - 1; ++s) {
        asm volatile("s_waitcnt vmcnt(4)" ::: "memory");
        __builtin_amdgcn_s_barrier();
        mfma_step1(As[s & 1], Ws[s & 1], acc, wm, wn, row_in, qs);
        __builtin_amdgcn_s_barrier();
        if (s < NST - 2) {
            int t = s + 2;
            const bf16* A = (t >= KSTEPS) ? A1 : A0;
            const bf16* W = (t >= KSTEPS) ? W1 : W0;
            int kk = (t >= KSTEPS) ? t - KSTEPS : t;
            stage_tile(A, m0, kk*TK, As[s & 1], tid);
            stage_tile(W, n0, kk*TK, Ws[s & 1], tid);
        }
    }
    asm volatile("s_waitcnt vmcnt(0)" ::: "memory");
    __builtin_amdgcn_s_barrier();
    mfma_step1(As[(NST-1) & 1], Ws[(NST-1) & 1], acc, wm, wn, row_in, qs);

    const int quad = lane >> 4;
#pragma unroll
    for (int i = 0; i < 4; ++i) {
#pragma unroll
        for (int j = 0; j < 4; ++j) {
            int n = n0 + wn + j*16 + row_in;
#pragma unroll
            for (int r = 0; r < 4; ++r) {
                int m = m0 + wm + i*16 + quad*4 + r;
                size_t o = (size_t)m*KP + n;
                if (n < N) {
                    float f = __bfloat162float(fx[o]);
                    float t = acc[i][j][r] + dv[n]*f;
                    O[o] = __float2bfloat16(gelu_f(t) + f);
                } else if (n < KP) {
                    O[o] = __float2bfloat16(0.f);
                }
            }
        }
    }
}

// ---------------- single GEMM + residual epilogue: h += acc + fy -----------
__global__ __launch_bounds__(256, 2) void gemmD_k(
    const bf16* __restrict__ A, const bf16* __restrict__ W,
    const bf16* __restrict__ fy, float* __restrict__ h, int N)
{
    __shared__ __align__(16) short As[2][TILE_SH];
    __shared__ __align__(16) short Ws[2][TILE_SH];
    const int tid  = threadIdx.x;
    int m0, n0;
    tile_coords(blockIdx.x, m0, n0);
    const int wave = tid >> 6, lane = tid & 63;
    const int wm = (wave >> 1) * 64, wn = (wave & 1) * 64;
    const int row_in = lane & 15;
    const int qs = (((lane >> 4) ^ (lane >> 1)) & 3) * 8;

    f32x4 acc[4][4] = {};

    stage_tile(A, m0, 0,  As[0], tid);
    stage_tile(W, n0, 0,  Ws[0], tid);
    stage_tile(A, m0, TK, As[1], tid);
    stage_tile(W, n0, TK, Ws[1], tid);

    for (int s = 0; s < KSTEPS - 1; ++s) {
        asm volatile("s_waitcnt vmcnt(4)" ::: "memory");
        __builtin_amdgcn_s_barrier();
        mfma_step1(As[s & 1], Ws[s & 1], acc, wm, wn, row_in, qs);
        __builtin_amdgcn_s_barrier();
        if (s < KSTEPS - 2) {
            const int k0 = (s + 2) * TK;
            stage_tile(A, m0, k0, As[s & 1], tid);
            stage_tile(W, n0, k0, Ws[s & 1], tid);
        }
    }
    asm volatile("s_waitcnt vmcnt(0)" ::: "memory");
    __builtin_amdgcn_s_barrier();
    mfma_step1(As[(KSTEPS-1) & 1], Ws[(KSTEPS-1) & 1], acc, wm, wn, row_in, qs);

    const int quad = lane >> 4;
#pragma unroll
    for (int i = 0; i < 4; ++i) {
#pragma unroll
        for (int j = 0; j < 4; ++j) {
            int n = n0 + wn + j*16 + row_in;
            if (n >= N) continue;
#pragma unroll
            for (int r = 0; r < 4; ++r) {
                int m = m0 + wm + i*16 + quad*4 + r;
                float f = __bfloat162float(fy[(size_t)m*KP + n]);
                h[(size_t)m*D_MODEL + n] += acc[i][j][r] + f;
            }
        }
    }
}

// ---------------- merged per-layer weight precompute -----------------------
// z=0: SSM prep (Bbar re/im + abar).  z=1..5: fp32->bf16 weight conversion
// (C_re, -C_im, WencA, WencG, Wdec) into w5.
__global__ __launch_bounds__(256) void prepconv_k(
    const float* __restrict__ lam_re, const float* __restrict__ lam_im,
    const float* __restrict__ log_step,
    const float* __restrict__ B_re, const float* __restrict__ B_im,
    bf16* __restrict__ bbar_re, bf16* __restrict__ bbar_im,
    float* __restrict__ abar,
    const float* __restrict__ s0, const float* __restrict__ s1,
    const float* __restrict__ s2, const float* __restrict__ s3,
    const float* __restrict__ s4, bf16* __restrict__ w5)
{
    size_t idx = (size_t)blockIdx.x*256 + threadIdx.x;
    if (idx >= NPKP) return;
    int z = blockIdx.z;
    int p = (int)(idx / KP);
    int d = (int)(idx - (size_t)p*KP);
    if (z == 0) {
        if (p >= P_DIM || d >= D_MODEL) {
            bbar_re[idx] = __float2bfloat16(0.f);
            bbar_im[idx] = __float2bfloat16(0.f);
            return;
        }
        float lr = lam_re[p], li = lam_im[p];
        float st = expf(log_step[p]);
        float er = expf(lr*st);
        float ar = er * cosf(li*st);
        float ai = er * sinf(li*st);
        if (d == 0) { abar[p] = ar; abar[P_DIM + p] = ai; }
        float den = lr*lr + li*li;
        float xr = ar - 1.f, xi = ai;
        float cr = (xr*lr + xi*li) / den;
        float ci = (xi*lr - xr*li) / den;
        float br = B_re[(size_t)p*D_MODEL + d], bi = B_im[(size_t)p*D_MODEL + d];
        bbar_re[idx] = __float2bfloat16(cr*br - ci*bi);
        bbar_im[idx] = __float2bfloat16(cr*bi + ci*br);
    } else {
        int w = z - 1;
        const float* src = (w == 0) ? s0 : (w == 1) ? s1 : (w == 2) ? s2 : (w == 3) ? s3 : s4;
        float scale = (w == 1) ? -1.f : 1.f;
        float v = (p < D_MODEL && d < D_MODEL) ? scale*src[(size_t)p*D_MODEL + d] : 0.f;
        w5[(size_t)w*NPKP + idx] = __float2bfloat16(v);
    }
}

// ---------------- reductions ----------------
__device__ __forceinline__ float2 block_reduce2(float a, float b) {
    __syncthreads();   // safe for repeated calls (shared reuse)
    for (int off = 32; off; off >>= 1) {
        a += __shfl_down(a, off, 64);
        b += __shfl_down(b, off, 64);
    }
    __shared__ float sa[4], sb[4];
    int lane = threadIdx.x & 63, wv = threadIdx.x >> 6;
    if (lane == 0) { sa[wv] = a; sb[wv] = b; }
    __syncthreads();
    if (threadIdx.x == 0) {
        sa[0] = sa[0]+sa[1]+sa[2]+sa[3];
        sb[0] = sb[0]+sb[1]+sb[2]+sb[3];
    }
    __syncthreads();
    return make_float2(sa[0], sb[0]);
}

// ---------------- fused double layernorm: fx = LN(LN(h,w1,b1),w2,b2) -------
// ENC=1: additionally computes h = x[row]*ew + eb itself and writes it (layer 0).
template <int ENC>
__global__ __launch_bounds__(256) void ln2x_k(
    const float* __restrict__ xin,
    const float* __restrict__ ew, const float* __restrict__ eb,
    float* __restrict__ hbuf,
    const float* __restrict__ w1, const float* __restrict__ bb1,
    const float* __restrict__ w2, const float* __restrict__ bb2,
    bf16* __restrict__ y)
{
    const size_t row = blockIdx.x;
    float v[5];
    float s = 0.f, ss = 0.f;
    int i = 0;
    if (ENC) {
        float xv = xin[row];
        float* hr = hbuf + row * D_MODEL;
        for (int d = threadIdx.x; d < KP; d += 256, ++i) {
            float t = 0.f;
            if (d < D_MODEL) { t = xv*ew[d] + eb[d]; hr[d] = t; }
            v[i] = t; s += t; ss += t*t;
        }
    } else {
        const float* xr = hbuf + row * D_MODEL;
        for (int d = threadIdx.x; d < KP; d += 256, ++i) {
            float t = (d < D_MODEL) ? xr[d] : 0.f;
            v[i] = t; s += t; ss += t*t;
        }
    }
    float2 r = block_reduce2(s, ss);
    float mu  = r.x * (1.f/D_MODEL);
    float var = r.y * (1.f/D_MODEL) - mu*mu;
    float inv = rsqrtf(var + 1e-5f);
    s = 0.f; ss = 0.f; i = 0;
    for (int d = threadIdx.x; d < KP; d += 256, ++i) {
        float z = (d < D_MODEL) ? (v[i]-mu)*inv*w1[d] + bb1[d] : 0.f;
        v[i] = z; s += z; ss += z*z;
    }
    r = block_reduce2(s, ss);
    mu  = r.x * (1.f/D_MODEL);
    var = r.y * (1.f/D_MODEL) - mu*mu;
    inv = rsqrtf(var + 1e-5f);
    bf16* yr = y + row * KP;
    i = 0;
    for (int d = threadIdx.x; d < KP; d += 256, ++i) {
        float o = (d < D_MODEL) ? (v[i]-mu)*inv*w2[d] + bb2[d] : 0.f;
        yr[d] = __float2bfloat16(o);
    }
}

// ---------------- single layernorm (bf16 in stride KP) ----------------
__global__ __launch_bounds__(256) void ln_k(
    const bf16* __restrict__ x, const float* __restrict__ w,
    const float* __restrict__ b, bf16* __restrict__ y)
{
    const size_t row = blockIdx.x;
    const bf16* xr = x + row * KP;
    float v[5];
    float s = 0.f, ss = 0.f;
    int i = 0;
    for (int d = threadIdx.x; d < KP; d += 256, ++i) {
        float t = (d < D_MODEL) ? __bfloat162float(xr[d]) : 0.f;
        v[i] = t; s += t; ss += t*t;
    }
    float2 r = block_reduce2(s, ss);
    float mu  = r.x * (1.f/D_MODEL);
    float var = r.y * (1.f/D_MODEL) - mu*mu;
    float inv = rsqrtf(var + 1e-5f);
    bf16* yr = y + row * KP;
    i = 0;
    for (int d = threadIdx.x; d < KP; d += 256, ++i) {
        float o = (d < D_MODEL) ? (v[i]-mu)*inv*w[d] + b[d] : 0.f;
        yr[d] = __float2bfloat16(o);
    }
}

// ---------------- chunked parallel scan (2 p per thread, ushort2) ----------
__device__ __forceinline__ float2 bf2f(unsigned int u) {
    unsigned int lo = u << 16, hi = u & 0xffff0000u;
    float2 r;
    r.x = __uint_as_float(lo);
    r.y = __uint_as_float(hi);
    return r;
}
__device__ __forceinline__ unsigned int f2bf2(float a, float b) {
    bf16 ba = __float2bfloat16(a), bb = __float2bfloat16(b);
    unsigned short ua = *(unsigned short*)&ba, ub = *(unsigned short*)&bb;
    return (unsigned int)ua | ((unsigned int)ub << 16);
}

__global__ __launch_bounds__(256) void scan_partial_k(
    const unsigned int* __restrict__ ur, const unsigned int* __restrict__ ui,
    const float* __restrict__ abar,
    float* __restrict__ sum_re, float* __restrict__ sum_im)
{
    int idx = blockIdx.x*256 + threadIdx.x;
    if (idx >= NSCAN2) return;
    int p2 = idx % P2;
    int rest = idx / P2;
    int c = rest % NC, b = rest / NC;
    int p = 2*p2;
    float ar0 = abar[p],   ai0 = abar[P_DIM + p];
    float ar1 = abar[p+1], ai1 = abar[P_DIM + p + 1];
    size_t base = (((size_t)b*LSEQ + (size_t)c*CL)*KP + p) >> 1;   // u32 index
    float s0r = 0.f, s0i = 0.f, s1r = 0.f, s1i = 0.f;
    for (int i = 0; i < CL; ++i) {
        size_t o = base + (size_t)i*(KP/2);
        float2 br = bf2f(ur[o]);
        float2 bi = bf2f(ui[o]);
        float n0r = fmaf(ar0, s0r, fmaf(-ai0, s0i, br.x));
        float n0i = fmaf(ar0, s0i, fmaf( ai0, s0r, bi.x));
        float n1r = fmaf(ar1, s1r, fmaf(-ai1, s1i, br.y));
        float n1i = fmaf(ar1, s1i, fmaf( ai1, s1r, bi.y));
        s0r = n0r; s0i = n0i; s1r = n1r; s1i = n1i;
    }
    size_t so = ((size_t)b*NC + c)*P_DIM + p;
    *(float2*)&sum_re[so] = make_float2(s0r, s1r);
    *(float2*)&sum_im[so] = make_float2(s0i, s1i);
}

__global__ __launch_bounds__(256) void scan_carry_k(
    const float* __restrict__ sum_re, const float* __restrict__ sum_im,
    const float* __restrict__ abar,
    float* __restrict__ car_re, float* __restrict__ car_im)
{
    int idx = blockIdx.x*256 + threadIdx.x;
    if (idx >= BSZ*P_DIM) return;
    int p = idx % P_DIM, b = idx / P_DIM;
    float cr = abar[p], ci = abar[P_DIM + p];
#pragma unroll
    for (int s = 0; s < 6; ++s) {       // a^64 by repeated squaring
        float nr = cr*cr - ci*ci;
        float ni = 2.f*cr*ci;
        cr = nr; ci = ni;
    }
    float xre = 0.f, xim = 0.f;
    size_t base = (size_t)b*NC*P_DIM + p;
    for (int c = 0; c < NC; ++c) {
        size_t o = base + (size_t)c*P_DIM;
        car_re[o] = xre; car_im[o] = xim;
        float sre = sum_re[o], sim = sum_im[o];
        float nr = fmaf(cr, xre, fmaf(-ci, xim, sre));
        float ni = fmaf(cr, xim, fmaf( ci, xre, sim));
        xre = nr; xim = ni;
    }
}

__global__ __launch_bounds__(256) void scan_apply_k(
    unsigned int* __restrict__ ur, unsigned int* __restrict__ ui,
    const float* __restrict__ abar,
    const float* __restrict__ car_re, const float* __restrict__ car_im)
{
    int idx = blockIdx.x*256 + threadIdx.x;
    if (idx >= NSCAN2) return;
    int p2 = idx % P2;
    int rest = idx / P2;
    int c = rest % NC, b = rest / NC;
    int p = 2*p2;
    float ar0 = abar[p],   ai0 = abar[P_DIM + p];
    float ar1 = abar[p+1], ai1 = abar[P_DIM + p + 1];
    size_t co = ((size_t)b*NC + c)*P_DIM + p;
    float2 c_r = *(const float2*)&car_re[co];
    float2 c_i = *(const float2*)&car_im[co];
    float x0r = c_r.x, x0i = c_i.x, x1r = c_r.y, x1i = c_i.y;
    size_t base = (((size_t)b*LSEQ + (size_t)c*CL)*KP + p) >> 1;
    for (int i = 0; i < CL; ++i) {
        size_t o = base + (size_t)i*(KP/2);
        float2 br = bf2f(ur[o]);
        float2 bi = bf2f(ui[o]);
        float n0r = fmaf(ar0, x0r, fmaf(-ai0, x0i, br.x));
        float n0i = fmaf(ar0, x0i, fmaf( ai0, x0r, bi.x));
        float n1r = fmaf(ar1, x1r, fmaf(-ai1, x1i, br.y));
        float n1i = fmaf(ar1, x1i, fmaf( ai1, x1r, bi.y));
        x0r = n0r; x0i = n0i; x1r = n1r; x1i = n1i;
        ur[o] = f2bf2(x0r, x1r);
        ui[o] = f2bf2(x0i, x1i);
    }
}

// ---------------- head ----------------
__global__ void head_init_k(float* out, const float* hb)
{
    if (threadIdx.x < BSZ) out[threadIdx.x] = hb[0];
}

__global__ __launch_bounds__(256) void head_k(
    const float* __restrict__ h, const float* __restrict__ hw,
    float* __restrict__ out)
{
    int b = blockIdx.x;
    int chunk = blockIdx.y;
    const float* hb = h + ((size_t)b*LSEQ + (size_t)chunk*64)*D_MODEL;
    float s = 0.f;
    for (int l = 0; l < 64; ++l) {
        const float* hr = hb + (size_t)l*D_MODEL;
        for (int d = threadIdx.x; d < D_MODEL; d += 256)
            s += hr[d]*hw[d];
    }
    for (int off = 32; off; off >>= 1) s += __shfl_down(s, off, 64);
    __shared__ float sm[4];
    int lane = threadIdx.x & 63, wv = threadIdx.x >> 6;
    if (lane == 0) sm[wv] = s;
    __syncthreads();
    if (threadIdx.x == 0)
        atomicAdd(out + b, (sm[0]+sm[1]+sm[2]+sm[3]) * (1.f/LSEQ));
}

// ---------------- launch ----------------
extern "C" void kernel_launch(void* const* d_in, const int* in_sizes, int n_in,
                              void* d_out, int out_size, void* d_ws, size_t ws_size,
                              hipStream_t stream)
{
    const float* x          = (const float*)d_in[0];
    const float* enc_w      = (const float*)d_in[1];
    const float* enc_b      = (const float*)d_in[2];
    const float* norm_w     = (const float*)d_in[3];
    const float* norm_b     = (const float*)d_in[4];
    const float* attn_w     = (const float*)d_in[5];
    const float* attn_b     = (const float*)d_in[6];
    const float* ff_w       = (const float*)d_in[7];
    const float* ff_b       = (const float*)d_in[8];
    const float* lam_re     = (const float*)d_in[9];
    const float* lam_im     = (const float*)d_in[10];
    const float* log_step   = (const float*)d_in[11];
    const float* B_re       = (const float*)d_in[12];
    const float* B_im       = (const float*)d_in[13];
    const float* C_re       = (const float*)d_in[14];
    const float* C_im       = (const float*)d_in[15];
    const float* Dvec       = (const float*)d_in[16];
    const float* Wenc       = (const float*)d_in[17];
    const float* Wdec       = (const float*)d_in[18];
    const float* head_w     = (const float*)d_in[19];
    const float* head_b     = (const float*)d_in[20];
    float* out = (float*)d_out;

    // ---- workspace (~241 MB) ----
    float* h    = (float*)d_ws;            // BLD fp32
    bf16*  b1   = (bf16*)(h + BLD);        // BLA bf16 each
    bf16*  b2   = b1 + BLA;
    bf16*  b3   = b2 + BLA;
    bf16*  b4   = b3 + BLA;
    bf16*  wbr  = b4 + BLA;                // Bbar re/im
    bf16*  wbi  = wbr + NPKP;
    bf16*  w5   = wbi + NPKP;              // wcr,wci(-),wea,weg,wd contiguous
    bf16*  wcr  = w5;
    bf16*  wci  = w5 + NPKP;
    bf16*  wea  = w5 + 2*NPKP;
    bf16*  weg  = w5 + 3*NPKP;
    bf16*  wd   = w5 + 4*NPKP;
    float* abar = (float*)(w5 + 5*NPKP);   // 2*P fp32
    float* sum_re = abar + 2*P_DIM;
    float* sum_im = sum_re + NSCAN;
    float* car_re = sum_im + NSCAN;
    float* car_im = car_re + NSCAN;

    const int CV   = (int)((NPKP + 255)/256);
    const int SC_G = (NSCAN2 + 255)/256;
    const size_t pd = (size_t)P_DIM*D_MODEL;

    for (int i = 0; i < NLAYER; ++i) {
        const float* WencA = Wenc + (size_t)i*2*pd;
        const float* WencG = WencA + pd;
        // merged SSM prep + 5x weight conversion (one dispatch)
        prepconv_k<<<dim3(CV,1,6), 256, 0, stream>>>(
            lam_re + i*P_DIM, lam_im + i*P_DIM, log_step + i*P_DIM,
            B_re + i*pd, B_im + i*pd, wbr, wbi, abar,
            C_re + i*pd, C_im + i*pd, WencA, WencG, Wdec + i*pd, w5);

        // fx = LN(LN(h)); layer 0 computes and writes h = x*ew+eb itself
        if (i == 0)
            ln2x_k<1><<<BL, 256, 0, stream>>>(x, enc_w, enc_b, h,
                norm_w + i*D_MODEL, norm_b + i*D_MODEL,
                attn_w + i*D_MODEL, attn_b + i*D_MODEL, b2);
        else
            ln2x_k<0><<<BL, 256, 0, stream>>>(nullptr, nullptr, nullptr, h,
                norm_w + i*D_MODEL, norm_b + i*D_MODEL,
                attn_w + i*D_MODEL, attn_b + i*D_MODEL, b2);

        // Bu_re, Bu_im in one dual-output GEMM
        gemm2o_k<0><<<NGEMM, 512, 0, stream>>>(b2, wbr, wbi, b1, b3, P_DIM);

        // chunked parallel scan (in-place on b1/b3)
        scan_partial_k<<<SC_G, 256, 0, stream>>>((unsigned int*)b1, (unsigned int*)b3,
                                                 abar, sum_re, sum_im);
        scan_carry_k<<<(BSZ*P_DIM + 255)/256, 256, 0, stream>>>(sum_re, sum_im, abar, car_re, car_im);
        scan_apply_k<<<SC_G, 256, 0, stream>>>((unsigned int*)b1, (unsigned int*)b3,
                                               abar, car_re, car_im);

        // z2 = gelu(xs_re@C_re^T + xs_im@(-C_im)^T + Dvec*fx) + fx
        gemmC_k<<<NGEMM, 256, 0, stream>>>(b1, wcr, b3, wci, b2, Dvec + i*D_MODEL, b4, D_MODEL);

        // fy = LN(z2)
        ln_k<<<BL, 256, 0, stream>>>(b4, ff_w + i*D_MODEL, ff_b + i*D_MODEL, b1);

        // GEGLU MLP: b2 = (fy@WencA^T) * gelu(fy@WencG^T)
        gemm2o_k<1><<<NGEMM, 512, 0, stream>>>(b1, wea, weg, b2, nullptr, D_MODEL);

        // h += b2@Wdec^T + fy
        gemmD_k<<<NGEMM, 256, 0, stream>>>(b2, wd, b1, h, D_MODEL);
    }

    head_init_k<<<1, 64, 0, stream>>>(out, head_b);
    head_k<<<dim3(BSZ, 64), 256, 0, stream>>>(h, head_w, out);
}